// Round 4
// baseline (386.686 us; speedup 1.0000x reference)
//
#include <hip/hip_runtime.h>
#include <stdint.h>

// DSA sparse attention, MI355X. T=512 tok, H=128 heads, K=512 selected keys,
// C=576 (512 lora + 64 rope), S=8192 cache rows.
// Pipeline: prep (kv->bf16 + rope copy, SCALE folded), q_lat GEMM, scores GEMM,
// row softmax (writes A-fragment-swizzled P2), attn GEMM, out GEMM.
// GEMMs: 128x128 tile, BK=32, 4 waves x (4x4 of 16x16x32 bf16 MFMA), m90/m92:
// A[m=lane&15][k=quad*8+j], B[n=lane&15][k=quad*8+j], D col=lane&15 row=quad*4+reg.
//
// R1->R2: attn 32-way LDS write conflicts fixed (stage+padded transpose).
// R2->R3: XCD swizzle (grid x = shared-tile axis) + global_load_lds staging.
// R3->R4: transpose bank tuning - NEUTRAL: LDS-issue/critical-path bound.
// R4->R5: attn v4 - A-fragments from global (P2 swizzled by softmax), St
//         double-buffered DMA, 2 barriers/ks.
// R5->R6: merged prep; baseline: attn 87us MfmaUtil 15.7% conflict 1.05e7.
// R6->R7/R8: attn v5 - ds_read_b64_tr_b16 B-fragments from pre-permuted LDS
//         subtiles, Bs buffer deleted; scores "double buffer" (neutral!).
// R8->R9: counted-vmcnt pipelines (T3/T4). Diagnosis: scores 87us with
//         MfmaUtil 17% / VALU 9.6% / occ 26% -> nothing busy; __syncthreads
//         lowers to vmcnt(0) drain, exposing the freshly-issued gather every
//         iter. Fix: raw s_barrier + counted s_waitcnt vmcnt(N), depth-3
//         buffers in scores (vmcnt(8)) and attn (vmcnt(2), one barrier/iter)
//         so each gather gets ~2 iterations of flight.

#define SCALE 0.041666666666666664f  // (512+64)^-0.5

typedef __bf16 bf16x8 __attribute__((ext_vector_type(8)));
typedef float floatx4 __attribute__((ext_vector_type(4)));
typedef unsigned int uint32x2 __attribute__((ext_vector_type(2)));
typedef unsigned int uint32x4 __attribute__((ext_vector_type(4)));

static __device__ __forceinline__ unsigned short f2bf(float f) {
  unsigned int u = __builtin_bit_cast(unsigned int, f);
  u += 0x7FFF + ((u >> 16) & 1);  // RNE
  return (unsigned short)(u >> 16);
}
static __device__ __forceinline__ float bf2f(unsigned short h) {
  unsigned int u = ((unsigned int)h) << 16;
  return __builtin_bit_cast(float, u);
}
static __device__ __forceinline__ unsigned int pack2(float lo, float hi) {
  return (unsigned int)f2bf(lo) | ((unsigned int)f2bf(hi) << 16);
}
// async global->LDS, 16B per lane; LDS dest = wave base + lane*16 (m97 pattern)
static __device__ __forceinline__ void ldsdma16(const void* g, void* l) {
  __builtin_amdgcn_global_load_lds(
      (const __attribute__((address_space(1))) void*)g,
      (__attribute__((address_space(3))) void*)l, 16, 0, 0);
}
// 32-bit LDS byte address for inline-asm DS ops
static __device__ __forceinline__ unsigned int lds_addr(const void* p) {
  return (unsigned int)(unsigned long long)(
      (__attribute__((address_space(3))) const void*)p);
}
// hardware transpose read: lane l gets column (l&15) of the 4x16 bf16 subtile
// addressed by its 16-lane group (per-lane addr = subtile_base + (l&15)*8B)
#define TR64(dst, addr, OFF) \
  asm volatile("ds_read_b64_tr_b16 %0, %1 offset:" OFF : "=v"(dst) : "v"(addr))

// stage 8 fp32 -> 8 bf16 into LDS (16B aligned)
static __device__ __forceinline__ void stage8_f32(const float* __restrict__ src,
                                                  unsigned short* dst) {
  const float4* s4 = reinterpret_cast<const float4*>(src);
  float4 v0 = s4[0], v1 = s4[1];
  uint4 o;
  o.x = pack2(v0.x, v0.y); o.y = pack2(v0.z, v0.w);
  o.z = pack2(v1.x, v1.y); o.w = pack2(v1.z, v1.w);
  *reinterpret_cast<uint4*>(dst) = o;
}

static __device__ __forceinline__ void mfma_4x4(const unsigned short* As,
                                                const unsigned short* Bs,
                                                int wm, int wn, int l15, int quad,
                                                floatx4 acc[4][4]) {
  bf16x8 af[4], bfr[4];
#pragma unroll
  for (int i = 0; i < 4; ++i)
    af[i] = *reinterpret_cast<const bf16x8*>(&As[(wm + i * 16 + l15) * 32 + quad * 8]);
#pragma unroll
  for (int j = 0; j < 4; ++j)
    bfr[j] = *reinterpret_cast<const bf16x8*>(&Bs[(wn + j * 16 + l15) * 32 + quad * 8]);
#pragma unroll
  for (int i = 0; i < 4; ++i)
#pragma unroll
    for (int j = 0; j < 4; ++j)
      acc[i][j] = __builtin_amdgcn_mfma_f32_16x16x32_bf16(af[i], bfr[j], acc[i][j], 0, 0, 0);
}

// ---------------- K0: kv_cache fp32 -> bf16  +  q_rope * SCALE -> q_concat ----------------
__global__ void prep(const float* __restrict__ kv, unsigned short* __restrict__ kvb,
                     const float* __restrict__ q, unsigned short* __restrict__ qc) {
  int b = blockIdx.x;
  if (b < 4608) {
    int i = b * 256 + threadIdx.x;  // per 4 elems, range sized exactly
    float4 v = reinterpret_cast<const float4*>(kv)[i];
    ushort4 o;
    o.x = f2bf(v.x); o.y = f2bf(v.y); o.z = f2bf(v.z); o.w = f2bf(v.w);
    reinterpret_cast<ushort4*>(kvb)[i] = o;
  } else {
    int i = (b - 4608) * 256 + threadIdx.x;  // 512*128*64 total
    int r = i & 63;
    int th = i >> 6;  // t*128 + h
    qc[(size_t)th * 576 + 512 + r] = f2bf(q[(size_t)th * 192 + 128 + r] * SCALE);
  }
}

// ---------------- K1: q_lat = per-head (T x 128) @ (512 x 128)^T, * SCALE ----------------
__global__ __launch_bounds__(256) void qlat_gemm(const float* __restrict__ q,
                                                 const float* __restrict__ kb,
                                                 unsigned short* __restrict__ qc) {
  const int h = blockIdx.x;
  const int tm = (blockIdx.y & 3) * 128;   // token tile
  const int tn = (blockIdx.y >> 2) * 128;  // lora-dim tile
  __shared__ __align__(16) unsigned short As[128 * 32];
  __shared__ __align__(16) unsigned short Bs[128 * 32];
  const int tid = threadIdx.x;
  const int lane = tid & 63, wave = tid >> 6;
  const int wm = (wave & 1) * 64, wn = (wave >> 1) * 64;
  const int l15 = lane & 15, quad = lane >> 4;
  const int r0 = tid >> 2, cg = tid & 3;  // chunk row, col-group(8)
  const float* a0 = q + ((size_t)(tm + r0) * 128 + h) * 192 + cg * 8;
  const float* a1 = q + ((size_t)(tm + r0 + 64) * 128 + h) * 192 + cg * 8;
  const float* b0 = kb + ((size_t)h * 512 + tn + r0) * 128 + cg * 8;
  const float* b1 = b0 + (size_t)64 * 128;
  floatx4 acc[4][4] = {};
  for (int ks = 0; ks < 4; ++ks) {  // contraction 128 = 4*32
    stage8_f32(a0 + ks * 32, &As[tid * 8]);
    stage8_f32(a1 + ks * 32, &As[2048 + tid * 8]);
    stage8_f32(b0 + ks * 32, &Bs[tid * 8]);
    stage8_f32(b1 + ks * 32, &Bs[2048 + tid * 8]);
    __syncthreads();
    mfma_4x4(As, Bs, wm, wn, l15, quad, acc);
    __syncthreads();
  }
#pragma unroll
  for (int i = 0; i < 4; ++i) {
    const int row = wm + i * 16 + quad * 4;  // token-local
#pragma unroll
    for (int j = 0; j < 4; ++j) {
      const int col = wn + j * 16 + l15;  // lora-dim-local
#pragma unroll
      for (int r = 0; r < 4; ++r) {
        const int t = tm + row + r;
        qc[((size_t)t * 128 + h) * 576 + tn + col] = f2bf(acc[i][j][r] * SCALE);
      }
    }
  }
}

// ---------------- K2: scores (128h x 128key tile) = Qc @ KVsel^T ----------------
// grid (512, 4): x = t. Depth-3 pipeline, counted vmcnt: per iter issue
// DMA(ks+2), wait vmcnt(8) (= DMA(ks) landed, 8 newer stay in flight), raw
// s_barrier both sides of the MFMA (no vmcnt(0) drain anywhere in the loop).
__global__ __launch_bounds__(256) void scores_gemm(const unsigned short* __restrict__ qc,
                                                   const unsigned short* __restrict__ kvb,
                                                   const int* __restrict__ topk,
                                                   unsigned short* __restrict__ P) {
  const int t = blockIdx.x;
  const int tn = blockIdx.y * 128;  // key tile
  __shared__ __align__(16) unsigned short As[3][128 * 32];
  __shared__ __align__(16) unsigned short Bs[3][128 * 32];
  const int tid = threadIdx.x;
  const int lane = tid & 63, wave = tid >> 6;
  const int wm = (wave & 1) * 64, wn = (wave >> 1) * 64;
  const int l15 = lane & 15, quad = lane >> 4;
  const int r0 = tid >> 2, cg = tid & 3;
  const unsigned short* a0 = qc + ((size_t)t * 128 + r0) * 576 + cg * 8;
  const unsigned short* a1 = a0 + (size_t)64 * 576;
  const int idx0 = topk[t * 512 + tn + r0];
  const int idx1 = topk[t * 512 + tn + r0 + 64];
  const unsigned short* b0 = kvb + (size_t)idx0 * 576 + cg * 8;
  const unsigned short* b1 = kvb + (size_t)idx1 * 576 + cg * 8;
  floatx4 acc[4][4] = {};
  // prologue: ks=0 -> buf0, ks=1 -> buf1 (8 DMA ops outstanding)
#pragma unroll
  for (int p = 0; p < 2; ++p) {
    ldsdma16(a0 + p * 32, &As[p][tid * 8]);
    ldsdma16(a1 + p * 32, &As[p][2048 + tid * 8]);
    ldsdma16(b0 + p * 32, &Bs[p][tid * 8]);
    ldsdma16(b1 + p * 32, &Bs[p][2048 + tid * 8]);
  }
  int bi = 0, bn = 2;  // read buffer, prefetch buffer (=(ks+2)%3)
  for (int ks = 0; ks < 18; ++ks) {  // contraction 576 = 18*32
    if (ks < 16) {
      ldsdma16(a0 + (ks + 2) * 32, &As[bn][tid * 8]);
      ldsdma16(a1 + (ks + 2) * 32, &As[bn][2048 + tid * 8]);
      ldsdma16(b0 + (ks + 2) * 32, &Bs[bn][tid * 8]);
      ldsdma16(b1 + (ks + 2) * 32, &Bs[bn][2048 + tid * 8]);
      asm volatile("s_waitcnt vmcnt(8)" ::: "memory");   // DMA(ks) landed
    } else if (ks == 16) {
      asm volatile("s_waitcnt vmcnt(4)" ::: "memory");
    } else {
      asm volatile("s_waitcnt vmcnt(0)" ::: "memory");
    }
    __builtin_amdgcn_s_barrier();  // all waves' DMA(ks) landed -> reads safe
    mfma_4x4(As[bi], Bs[bi], wm, wn, l15, quad, acc);
    __builtin_amdgcn_s_barrier();  // reads of buf[bi] done -> next iter may DMA it
    bi = bi == 2 ? 0 : bi + 1;
    bn = bn == 2 ? 0 : bn + 1;
  }
#pragma unroll
  for (int i = 0; i < 4; ++i) {
    const int row = wm + i * 16 + quad * 4;  // head
#pragma unroll
    for (int j = 0; j < 4; ++j) {
      const int col = tn + wn + j * 16 + l15;  // key
#pragma unroll
      for (int r = 0; r < 4; ++r)
        P[((size_t)t * 128 + row + r) * 512 + col] = f2bf(acc[i][j][r]);
    }
  }
}

// ---------------- K3: softmax rows of 512; writes P2 in A-fragment order ----------------
__global__ __launch_bounds__(256) void softmax_rows(const unsigned short* __restrict__ Pin,
                                                    unsigned short* __restrict__ P2) {
  const int row = blockIdx.x * 4 + (threadIdx.x >> 6);  // t*128 + h
  const int t = row >> 7, h = row & 127;
  const int lane = threadIdx.x & 63;
  const unsigned short* rp = Pin + (size_t)row * 512 + lane * 8;
  uint4 raw = *reinterpret_cast<const uint4*>(rp);
  unsigned int w[4] = {raw.x, raw.y, raw.z, raw.w};
  float f[8];
  float mx = -1e30f;
#pragma unroll
  for (int i = 0; i < 8; ++i) {
    f[i] = bf2f((unsigned short)((w[i >> 1] >> ((i & 1) * 16)) & 0xFFFF));
    mx = fmaxf(mx, f[i]);
  }
#pragma unroll
  for (int off = 32; off; off >>= 1) mx = fmaxf(mx, __shfl_xor(mx, off, 64));
  float s = 0.f;
#pragma unroll
  for (int i = 0; i < 8; ++i) { f[i] = __expf(f[i] - mx); s += f[i]; }
#pragma unroll
  for (int off = 32; off; off >>= 1) s += __shfl_xor(s, off, 64);
  const float inv = 1.0f / s;
  uint4 o;
  o.x = pack2(f[0] * inv, f[1] * inv);
  o.y = pack2(f[2] * inv, f[3] * inv);
  o.z = pack2(f[4] * inv, f[5] * inv);
  o.w = pack2(f[6] * inv, f[7] * inv);
  unsigned short* wp =
      P2 + (((size_t)t * 16 + (lane >> 2)) * 128 + h) * 32 + (lane & 3) * 8;
  *reinterpret_cast<uint4*>(wp) = o;
}

// ---------------- K4: attn_lat (128h x 128c tile) = P @ KVsel[:, :512] ----------------
// grid (512, 4): x = t. A-fragments from swizzled P2 (global, reg-prefetched).
// St depth-3, linear LDS = subtiled [kq][ct][4][16] via pre-permuted DMA src;
// B-fragments via ds_read_b64_tr_b16. One raw barrier/iter + counted vmcnt(2):
// per iter issue order a_nxt -> idx(ks+3) -> DMA(ks+2) keeps the DMA youngest,
// so vmcnt(2) at the top drains exactly {DMA(ks), a_nxt(ks), idx(ks+2)} while
// DMA(ks+1) (in flight since iter ks-1) crosses the barrier untouched.
__global__ __launch_bounds__(256) void attn_gemm(const unsigned short* __restrict__ P2,
                                                 const unsigned short* __restrict__ kvb,
                                                 const int* __restrict__ topk,
                                                 unsigned short* __restrict__ alat) {
  const int t = blockIdx.x;
  const int tn = blockIdx.y * 128;  // c-dim tile
  __shared__ __align__(16) unsigned short St[3][32 * 128];
  const int tid = threadIdx.x;
  const int lane = tid & 63, wave = tid >> 6;
  const int wm = (wave & 1) * 64, wn = (wave >> 1) * 64;
  const int l15 = lane & 15, quad = lane >> 4;
  // DMA source permutation: thread tid fetches (keyA, cA) so lane-linear LDS
  // dest realizes the subtiled layout.
  const int keyA = wave * 4 + ((tid >> 1) & 3);            // 0..15
  const int cA = ((tid >> 3) & 7) * 16 + (tid & 1) * 8;    // 0..120
  const int* tkrow = topk + t * 512;
  // A-fragment base: P2[((t*16+ks)*128 + wm+i*16+l15)*32 + quad*8]
  const unsigned short* a_base =
      P2 + ((size_t)t * 16 * 128 + wm + l15) * 32 + quad * 8;
  // tr_read lane base: subtile (kq=2*quad+h, ct=wn/16+j) at byte
  // (kq*8+ct)*128 + l15*8 = quad*2048 + wn*8 + l15*8 + h*1024 + j*128
  const unsigned int tra0 = lds_addr(&St[0][0]) + quad * 2048 + wn * 8 + l15 * 8;
  floatx4 acc[4][4] = {};
  bf16x8 a_cur[4], a_nxt[4];
  int i0p, i1p;  // prefetched gather indices (2 tiles ahead)
  {
    const int i00 = tkrow[keyA], i10 = tkrow[16 + keyA];
    ldsdma16(kvb + (size_t)i00 * 576 + tn + cA, &St[0][tid * 8]);
    ldsdma16(kvb + (size_t)i10 * 576 + tn + cA, &St[0][2048 + tid * 8]);
    i0p = tkrow[64 + keyA];   // idx(2)
    i1p = tkrow[80 + keyA];
#pragma unroll
    for (int i = 0; i < 4; ++i)
      a_cur[i] = *reinterpret_cast<const bf16x8*>(a_base + (size_t)i * 16 * 32);
    const int i01 = tkrow[32 + keyA], i11 = tkrow[48 + keyA];
    ldsdma16(kvb + (size_t)i01 * 576 + tn + cA, &St[1][tid * 8]);  // youngest
    ldsdma16(kvb + (size_t)i11 * 576 + tn + cA, &St[1][2048 + tid * 8]);
  }
  int sti = 0, std2 = 2;  // read buffer, prefetch buffer (=(ks+2)%3)
  for (int ks = 0; ks < 16; ++ks) {
    if (ks < 15) asm volatile("s_waitcnt vmcnt(2)" ::: "memory");  // DMA(ks) landed
    else         asm volatile("s_waitcnt vmcnt(0)" ::: "memory");
    __builtin_amdgcn_s_barrier();  // St[sti] full for all waves; St[std2] free
    const unsigned int tra = tra0 + sti * 8192;
    uint32x2 r00, r01, r10, r11, r20, r21, r30, r31;
    TR64(r00, tra, "0");   TR64(r01, tra, "1024");
    TR64(r10, tra, "128"); TR64(r11, tra, "1152");
    TR64(r20, tra, "256"); TR64(r21, tra, "1280");
    TR64(r30, tra, "384"); TR64(r31, tra, "1408");
    if (ks < 15) {
#pragma unroll
      for (int i = 0; i < 4; ++i)
        a_nxt[i] = *reinterpret_cast<const bf16x8*>(
            a_base + ((size_t)(ks + 1) * 128 + i * 16) * 32);
    }
    if (ks < 14) {
      const int d0 = i0p, d1 = i1p;  // idx(ks+2)
      if (ks < 13) {
        i0p = tkrow[(ks + 3) * 32 + keyA];
        i1p = tkrow[(ks + 3) * 32 + 16 + keyA];
      }
      ldsdma16(kvb + (size_t)d0 * 576 + tn + cA, &St[std2][tid * 8]);
      ldsdma16(kvb + (size_t)d1 * 576 + tn + cA, &St[std2][2048 + tid * 8]);
    }
    asm volatile("s_waitcnt lgkmcnt(0)");   // tr_reads complete
    __builtin_amdgcn_sched_barrier(0);      // rule #18: pin MFMAs after the wait
    bf16x8 bfr[4];
    {
      uint32x4 w;
      w.x = r00.x; w.y = r00.y; w.z = r01.x; w.w = r01.y;
      bfr[0] = __builtin_bit_cast(bf16x8, w);
      w.x = r10.x; w.y = r10.y; w.z = r11.x; w.w = r11.y;
      bfr[1] = __builtin_bit_cast(bf16x8, w);
      w.x = r20.x; w.y = r20.y; w.z = r21.x; w.w = r21.y;
      bfr[2] = __builtin_bit_cast(bf16x8, w);
      w.x = r30.x; w.y = r30.y; w.z = r31.x; w.w = r31.y;
      bfr[3] = __builtin_bit_cast(bf16x8, w);
    }
#pragma unroll
    for (int i = 0; i < 4; ++i)
#pragma unroll
      for (int j = 0; j < 4; ++j)
        acc[i][j] =
            __builtin_amdgcn_mfma_f32_16x16x32_bf16(a_cur[i], bfr[j], acc[i][j], 0, 0, 0);
#pragma unroll
    for (int i = 0; i < 4; ++i) a_cur[i] = a_nxt[i];
    sti = sti == 2 ? 0 : sti + 1;
    std2 = std2 == 2 ? 0 : std2 + 1;
  }
  // write attn_lat in (H, T, 512) layout for K5's contiguous A reads
#pragma unroll
  for (int i = 0; i < 4; ++i) {
    const int row = wm + i * 16 + quad * 4;  // head
#pragma unroll
    for (int j = 0; j < 4; ++j) {
      const int col = tn + wn + j * 16 + l15;  // c
#pragma unroll
      for (int r = 0; r < 4; ++r)
        alat[((size_t)(row + r) * 512 + t) * 512 + col] = f2bf(acc[i][j][r]);
    }
  }
}

// ---------------- K5: out (128t x 128v tile) = attn_lat[h] @ v_b[h]^T ----------------
__global__ __launch_bounds__(256) void out_gemm(const unsigned short* __restrict__ alat,
                                                const float* __restrict__ vb,
                                                float* __restrict__ out) {
  const int h = blockIdx.x;
  const int tm = blockIdx.y * 128;  // token tile
  __shared__ __align__(16) unsigned short As[128 * 32];
  __shared__ __align__(16) unsigned short Bs[128 * 32];
  const int tid = threadIdx.x;
  const int lane = tid & 63, wave = tid >> 6;
  const int wm = (wave & 1) * 64, wn = (wave >> 1) * 64;
  const int l15 = lane & 15, quad = lane >> 4;
  const int r0 = tid >> 2, cg = tid & 3;
  const unsigned short* a0 = alat + ((size_t)h * 512 + tm + r0) * 512 + cg * 8;
  const unsigned short* a1 = a0 + (size_t)64 * 512;
  const float* b0 = vb + ((size_t)h * 128 + r0) * 512 + cg * 8;
  const float* b1 = b0 + (size_t)64 * 512;
  floatx4 acc[4][4] = {};
  for (int ks = 0; ks < 16; ++ks) {  // contraction 512 = 16*32
    ldsdma16(a0 + ks * 32, &As[tid * 8]);
    ldsdma16(a1 + ks * 32, &As[2048 + tid * 8]);
    stage8_f32(b0 + ks * 32, &Bs[tid * 8]);
    stage8_f32(b1 + ks * 32, &Bs[2048 + tid * 8]);
    __syncthreads();
    mfma_4x4(As, Bs, wm, wn, l15, quad, acc);
    __syncthreads();
  }
#pragma unroll
  for (int i = 0; i < 4; ++i) {
    const int row = wm + i * 16 + quad * 4;  // token-local
#pragma unroll
    for (int j = 0; j < 4; ++j) {
      const int col = wn + j * 16 + l15;  // v
#pragma unroll
      for (int r = 0; r < 4; ++r) {
        const int t = tm + row + r;
        out[((size_t)t * 128 + h) * 128 + col] = acc[i][j][r];
      }
    }
  }
}

extern "C" void kernel_launch(void* const* d_in, const int* in_sizes, int n_in,
                              void* d_out, int out_size, void* d_ws, size_t ws_size,
                              hipStream_t stream) {
  const float* q = (const float*)d_in[0];         // (512,128,192)
  const float* kv = (const float*)d_in[1];        // (8192,576)
  const int* topk = (const int*)d_in[2];          // (512,512)
  const float* kb = (const float*)d_in[3];        // (128,512,128)
  const float* vb = (const float*)d_in[4];        // (128,128,512)
  float* out = (float*)d_out;                     // (512,128,128)

  char* ws = (char*)d_ws;
  unsigned short* kvb = (unsigned short*)ws;                       // 9,437,184 B
  unsigned short* qc = (unsigned short*)(ws + 9437184);            // 75,497,472 B
  unsigned short* P = (unsigned short*)(ws + 9437184 + 75497472);  // 67,108,864 B
  // lifetime reuse (no growth, 152 MB total):
  unsigned short* P2 = qc;    // qc dead after scores_gemm; softmax writes here
  unsigned short* alat = P;   // P dead after softmax; attn writes here

  prep<<<dim3(20992), dim3(256), 0, stream>>>(kv, kvb, q, qc);
  qlat_gemm<<<dim3(128, 16), dim3(256), 0, stream>>>(q, kb, qc);
  scores_gemm<<<dim3(512, 4), dim3(256), 0, stream>>>(qc, kvb, topk, P);
  softmax_rows<<<dim3(16384), dim3(256), 0, stream>>>(P, P2);
  attn_gemm<<<dim3(512, 4), dim3(256), 0, stream>>>(P2, kvb, topk, alat);
  out_gemm<<<dim3(128, 4), dim3(256), 0, stream>>>(alat, vb, out);
}

// Round 6
// 383.904 us; speedup vs baseline: 1.0072x; 1.0072x over previous
//
#include <hip/hip_runtime.h>
#include <stdint.h>

// DSA sparse attention, MI355X. T=512 tok, H=128 heads, K=512 selected keys,
// C=576 (512 lora + 64 rope), S=8192 cache rows.
// Pipeline: prep (kv->bf16 + rope copy, SCALE folded), q_lat GEMM, scores GEMM,
// row softmax (writes A-fragment-swizzled P2), attn GEMM, out GEMM.
// MFMA tiling per m90/m92: A[m=lane&15][k=quad*8+j], B[n=lane&15][k=quad*8+j],
// D col=lane&15 row=quad*4+reg.
//
// R5->R6: merged prep; baseline: attn 87us MfmaUtil 15.7% conflict 1.05e7.
// R6->R7/R8: attn ds_read_b64_tr_b16 B-fragments from pre-permuted LDS
//         subtiles (works, attn ~80); scores dbuf (neutral).
// R8->R9: counted-vmcnt depth-3 pipelines: NEUTRAL. scores pinned 85-88us
//         across 3 schedules -> memory-path throughput wall, not latency.
// R9->R10: traffic reduction round.
//   attn v6: merged c-tiles - ONE 512-thread/8-wave block per token computes
//         128h x 512c (acc 4x8, 128 VGPR). P2 A-frags read 1x (268->67MB);
//         kvb gather uses 1KB of each row per block (was 256B). St 32k x 512c
//         subtiled for tr_read, depth-3 (96KB LDS), counted vmcnt(4).
//   grid order: siblings sharing an operand made consecutive (co-resident,
//         L3-temporal): scores (4,512) share A(t); qlat (16,128) share B(h);
//         out (4,128) share B(h). Was 512-apart -> 4x refetch amplification.
// R10->R11: infra-failed round; resubmit unchanged after paper audit (DMA
//         permutation inverse, tr_read bases, vmcnt(4) edge at ks=15 -- all
//         check out; the memory-clobber asm waits pin the vm queue order).

#define SCALE 0.041666666666666664f  // (512+64)^-0.5

typedef __bf16 bf16x8 __attribute__((ext_vector_type(8)));
typedef float floatx4 __attribute__((ext_vector_type(4)));
typedef unsigned int uint32x2 __attribute__((ext_vector_type(2)));
typedef unsigned int uint32x4 __attribute__((ext_vector_type(4)));

static __device__ __forceinline__ unsigned short f2bf(float f) {
  unsigned int u = __builtin_bit_cast(unsigned int, f);
  u += 0x7FFF + ((u >> 16) & 1);  // RNE
  return (unsigned short)(u >> 16);
}
static __device__ __forceinline__ float bf2f(unsigned short h) {
  unsigned int u = ((unsigned int)h) << 16;
  return __builtin_bit_cast(float, u);
}
static __device__ __forceinline__ unsigned int pack2(float lo, float hi) {
  return (unsigned int)f2bf(lo) | ((unsigned int)f2bf(hi) << 16);
}
// async global->LDS, 16B per lane; LDS dest = wave base + lane*16 (m97 pattern)
static __device__ __forceinline__ void ldsdma16(const void* g, void* l) {
  __builtin_amdgcn_global_load_lds(
      (const __attribute__((address_space(1))) void*)g,
      (__attribute__((address_space(3))) void*)l, 16, 0, 0);
}
// 32-bit LDS byte address for inline-asm DS ops
static __device__ __forceinline__ unsigned int lds_addr(const void* p) {
  return (unsigned int)(unsigned long long)(
      (__attribute__((address_space(3))) const void*)p);
}
// hardware transpose read: lane l gets column (l&15) of the 4x16 bf16 subtile
#define TR64(dst, addr, OFF) \
  asm volatile("ds_read_b64_tr_b16 %0, %1 offset:" OFF : "=v"(dst) : "v"(addr))

// stage 8 fp32 -> 8 bf16 into LDS (16B aligned)
static __device__ __forceinline__ void stage8_f32(const float* __restrict__ src,
                                                  unsigned short* dst) {
  const float4* s4 = reinterpret_cast<const float4*>(src);
  float4 v0 = s4[0], v1 = s4[1];
  uint4 o;
  o.x = pack2(v0.x, v0.y); o.y = pack2(v0.z, v0.w);
  o.z = pack2(v1.x, v1.y); o.w = pack2(v1.z, v1.w);
  *reinterpret_cast<uint4*>(dst) = o;
}

static __device__ __forceinline__ void mfma_4x4(const unsigned short* As,
                                                const unsigned short* Bs,
                                                int wm, int wn, int l15, int quad,
                                                floatx4 acc[4][4]) {
  bf16x8 af[4], bfr[4];
#pragma unroll
  for (int i = 0; i < 4; ++i)
    af[i] = *reinterpret_cast<const bf16x8*>(&As[(wm + i * 16 + l15) * 32 + quad * 8]);
#pragma unroll
  for (int j = 0; j < 4; ++j)
    bfr[j] = *reinterpret_cast<const bf16x8*>(&Bs[(wn + j * 16 + l15) * 32 + quad * 8]);
#pragma unroll
  for (int i = 0; i < 4; ++i)
#pragma unroll
    for (int j = 0; j < 4; ++j)
      acc[i][j] = __builtin_amdgcn_mfma_f32_16x16x32_bf16(af[i], bfr[j], acc[i][j], 0, 0, 0);
}

// ---------------- K0: kv_cache fp32 -> bf16  +  q_rope * SCALE -> q_concat ----------------
__global__ void prep(const float* __restrict__ kv, unsigned short* __restrict__ kvb,
                     const float* __restrict__ q, unsigned short* __restrict__ qc) {
  int b = blockIdx.x;
  if (b < 4608) {
    int i = b * 256 + threadIdx.x;  // per 4 elems, range sized exactly
    float4 v = reinterpret_cast<const float4*>(kv)[i];
    ushort4 o;
    o.x = f2bf(v.x); o.y = f2bf(v.y); o.z = f2bf(v.z); o.w = f2bf(v.w);
    reinterpret_cast<ushort4*>(kvb)[i] = o;
  } else {
    int i = (b - 4608) * 256 + threadIdx.x;  // 512*128*64 total
    int r = i & 63;
    int th = i >> 6;  // t*128 + h
    qc[(size_t)th * 576 + 512 + r] = f2bf(q[(size_t)th * 192 + 128 + r] * SCALE);
  }
}

// ---------------- K1: q_lat = per-head (T x 128) @ (512 x 128)^T, * SCALE ----------------
// grid (16, 128): y = h; the 16 tile-blocks of one head are CONSECUTIVE.
__global__ __launch_bounds__(256) void qlat_gemm(const float* __restrict__ q,
                                                 const float* __restrict__ kb,
                                                 unsigned short* __restrict__ qc) {
  const int h = blockIdx.y;
  const int tm = (blockIdx.x & 3) * 128;   // token tile
  const int tn = (blockIdx.x >> 2) * 128;  // lora-dim tile
  __shared__ __align__(16) unsigned short As[128 * 32];
  __shared__ __align__(16) unsigned short Bs[128 * 32];
  const int tid = threadIdx.x;
  const int lane = tid & 63, wave = tid >> 6;
  const int wm = (wave & 1) * 64, wn = (wave >> 1) * 64;
  const int l15 = lane & 15, quad = lane >> 4;
  const int r0 = tid >> 2, cg = tid & 3;  // chunk row, col-group(8)
  const float* a0 = q + ((size_t)(tm + r0) * 128 + h) * 192 + cg * 8;
  const float* a1 = q + ((size_t)(tm + r0 + 64) * 128 + h) * 192 + cg * 8;
  const float* b0 = kb + ((size_t)h * 512 + tn + r0) * 128 + cg * 8;
  const float* b1 = b0 + (size_t)64 * 128;
  floatx4 acc[4][4] = {};
  for (int ks = 0; ks < 4; ++ks) {  // contraction 128 = 4*32
    stage8_f32(a0 + ks * 32, &As[tid * 8]);
    stage8_f32(a1 + ks * 32, &As[2048 + tid * 8]);
    stage8_f32(b0 + ks * 32, &Bs[tid * 8]);
    stage8_f32(b1 + ks * 32, &Bs[2048 + tid * 8]);
    __syncthreads();
    mfma_4x4(As, Bs, wm, wn, l15, quad, acc);
    __syncthreads();
  }
#pragma unroll
  for (int i = 0; i < 4; ++i) {
    const int row = wm + i * 16 + quad * 4;  // token-local
#pragma unroll
    for (int j = 0; j < 4; ++j) {
      const int col = wn + j * 16 + l15;  // lora-dim-local
#pragma unroll
      for (int r = 0; r < 4; ++r) {
        const int t = tm + row + r;
        qc[((size_t)t * 128 + h) * 576 + tn + col] = f2bf(acc[i][j][r] * SCALE);
      }
    }
  }
}

// ---------------- K2: scores (128h x 128key tile) = Qc @ KVsel^T ----------------
// grid (4, 512): y = t; the 4 key-tile blocks sharing A(t) are CONSECUTIVE
// (co-resident across XCDs, L3-temporal sharing). Depth-3 counted-vmcnt pipe.
__global__ __launch_bounds__(256) void scores_gemm(const unsigned short* __restrict__ qc,
                                                   const unsigned short* __restrict__ kvb,
                                                   const int* __restrict__ topk,
                                                   unsigned short* __restrict__ P) {
  const int t = blockIdx.y;
  const int tn = blockIdx.x * 128;  // key tile
  __shared__ __align__(16) unsigned short As[3][128 * 32];
  __shared__ __align__(16) unsigned short Bs[3][128 * 32];
  const int tid = threadIdx.x;
  const int lane = tid & 63, wave = tid >> 6;
  const int wm = (wave & 1) * 64, wn = (wave >> 1) * 64;
  const int l15 = lane & 15, quad = lane >> 4;
  const int r0 = tid >> 2, cg = tid & 3;
  const unsigned short* a0 = qc + ((size_t)t * 128 + r0) * 576 + cg * 8;
  const unsigned short* a1 = a0 + (size_t)64 * 576;
  const int idx0 = topk[t * 512 + tn + r0];
  const int idx1 = topk[t * 512 + tn + r0 + 64];
  const unsigned short* b0 = kvb + (size_t)idx0 * 576 + cg * 8;
  const unsigned short* b1 = kvb + (size_t)idx1 * 576 + cg * 8;
  floatx4 acc[4][4] = {};
  // prologue: ks=0 -> buf0, ks=1 -> buf1 (8 DMA ops outstanding)
#pragma unroll
  for (int p = 0; p < 2; ++p) {
    ldsdma16(a0 + p * 32, &As[p][tid * 8]);
    ldsdma16(a1 + p * 32, &As[p][2048 + tid * 8]);
    ldsdma16(b0 + p * 32, &Bs[p][tid * 8]);
    ldsdma16(b1 + p * 32, &Bs[p][2048 + tid * 8]);
  }
  int bi = 0, bn = 2;  // read buffer, prefetch buffer (=(ks+2)%3)
  for (int ks = 0; ks < 18; ++ks) {  // contraction 576 = 18*32
    if (ks < 16) {
      ldsdma16(a0 + (ks + 2) * 32, &As[bn][tid * 8]);
      ldsdma16(a1 + (ks + 2) * 32, &As[bn][2048 + tid * 8]);
      ldsdma16(b0 + (ks + 2) * 32, &Bs[bn][tid * 8]);
      ldsdma16(b1 + (ks + 2) * 32, &Bs[bn][2048 + tid * 8]);
      asm volatile("s_waitcnt vmcnt(8)" ::: "memory");   // DMA(ks) landed
    } else if (ks == 16) {
      asm volatile("s_waitcnt vmcnt(4)" ::: "memory");
    } else {
      asm volatile("s_waitcnt vmcnt(0)" ::: "memory");
    }
    __builtin_amdgcn_s_barrier();  // all waves' DMA(ks) landed -> reads safe
    mfma_4x4(As[bi], Bs[bi], wm, wn, l15, quad, acc);
    __builtin_amdgcn_s_barrier();  // reads of buf[bi] done -> next iter may DMA it
    bi = bi == 2 ? 0 : bi + 1;
    bn = bn == 2 ? 0 : bn + 1;
  }
#pragma unroll
  for (int i = 0; i < 4; ++i) {
    const int row = wm + i * 16 + quad * 4;  // head
#pragma unroll
    for (int j = 0; j < 4; ++j) {
      const int col = tn + wn + j * 16 + l15;  // key
#pragma unroll
      for (int r = 0; r < 4; ++r)
        P[((size_t)t * 128 + row + r) * 512 + col] = f2bf(acc[i][j][r]);
    }
  }
}

// ---------------- K3: softmax rows of 512; writes P2 in A-fragment order ----------------
__global__ __launch_bounds__(256) void softmax_rows(const unsigned short* __restrict__ Pin,
                                                    unsigned short* __restrict__ P2) {
  const int row = blockIdx.x * 4 + (threadIdx.x >> 6);  // t*128 + h
  const int t = row >> 7, h = row & 127;
  const int lane = threadIdx.x & 63;
  const unsigned short* rp = Pin + (size_t)row * 512 + lane * 8;
  uint4 raw = *reinterpret_cast<const uint4*>(rp);
  unsigned int w[4] = {raw.x, raw.y, raw.z, raw.w};
  float f[8];
  float mx = -1e30f;
#pragma unroll
  for (int i = 0; i < 8; ++i) {
    f[i] = bf2f((unsigned short)((w[i >> 1] >> ((i & 1) * 16)) & 0xFFFF));
    mx = fmaxf(mx, f[i]);
  }
#pragma unroll
  for (int off = 32; off; off >>= 1) mx = fmaxf(mx, __shfl_xor(mx, off, 64));
  float s = 0.f;
#pragma unroll
  for (int i = 0; i < 8; ++i) { f[i] = __expf(f[i] - mx); s += f[i]; }
#pragma unroll
  for (int off = 32; off; off >>= 1) s += __shfl_xor(s, off, 64);
  const float inv = 1.0f / s;
  uint4 o;
  o.x = pack2(f[0] * inv, f[1] * inv);
  o.y = pack2(f[2] * inv, f[3] * inv);
  o.z = pack2(f[4] * inv, f[5] * inv);
  o.w = pack2(f[6] * inv, f[7] * inv);
  unsigned short* wp =
      P2 + (((size_t)t * 16 + (lane >> 2)) * 128 + h) * 32 + (lane & 3) * 8;
  *reinterpret_cast<uint4*>(wp) = o;
}

// ---------------- K4: attn_lat = P @ KVsel[:, :512], FULL 128h x 512c per block ----------------
// grid (512): one block per token, 512 threads / 8 waves (wr=wave>>2 head-half,
// wc=wave&3 c-quarter), acc 4x8 frags. P2 A-fragments read ONCE per t.
// St[ks tile] = 32 keys x 512 c staged subtiled for tr_read: elem (key,c) at
// byte ((key>>2)*32 + (c>>4))*128 + (key&3)*32 + (c&15)*2; DMA source
// pre-permuted so lane-linear LDS realizes it. Depth-3 (96KB), vmcnt(4)/iter.
__global__ __launch_bounds__(512) void attn_gemm(const unsigned short* __restrict__ P2,
                                                 const unsigned short* __restrict__ kvb,
                                                 const int* __restrict__ topk,
                                                 unsigned short* __restrict__ alat) {
  const int t = blockIdx.x;
  __shared__ __align__(16) unsigned short St[3][32 * 512];
  const int tid = threadIdx.x;
  const int lane = tid & 63, wave = tid >> 6;
  const int wm = (wave >> 2) * 64;   // head base (0/64)
  const int wc = wave & 3;           // c-quarter
  const int l15 = lane & 15, quad = lane >> 4;
  // DMA permutation: thread tid, dma d: key = d*8 + (tid>>8)*4 + ((tid>>1)&3),
  // c = ((tid>>3)&31)*16 + (tid&1)*8  (16B per thread per d; 4 d = 32KB tile)
  const int keyBase = (tid >> 8) * 4 + ((tid >> 1) & 3);
  const int cA = ((tid >> 3) & 31) * 16 + (tid & 1) * 8;
  const int* tkrow = topk + t * 512;
  // A-fragment base: P2[((t*16+ks)*128 + wm+i*16+l15)*32 + quad*8]
  const unsigned short* a_base =
      P2 + ((size_t)t * 16 * 128 + wm + l15) * 32 + quad * 8;
  // tr_read base: subtile (kq=2*quad+h01, ct=wc*8+j) at byte (kq*32+ct)*128;
  // lane addr = quad*8192 + wc*1024 + l15*8; offsets j*128 (+4096 for h01=1)
  const unsigned int tra0 = lds_addr(&St[0][0]) + quad * 8192 + wc * 1024 + l15 * 8;
  floatx4 acc[4][8] = {};
  bf16x8 a_cur[4], a_nxt[4];
  int ip0, ip1, ip2, ip3;  // gather indices for tile ks+2
  {
#pragma unroll
    for (int d = 0; d < 4; ++d) {
      const int k0 = tkrow[d * 8 + keyBase];
      ldsdma16(kvb + (size_t)k0 * 576 + cA, &St[0][d * 4096 + tid * 8]);
    }
#pragma unroll
    for (int i = 0; i < 4; ++i)
      a_cur[i] = *reinterpret_cast<const bf16x8*>(a_base + (size_t)i * 16 * 32);
    ip0 = tkrow[64 + 0 * 8 + keyBase];
    ip1 = tkrow[64 + 1 * 8 + keyBase];
    ip2 = tkrow[64 + 2 * 8 + keyBase];
    ip3 = tkrow[64 + 3 * 8 + keyBase];
#pragma unroll
    for (int d = 0; d < 4; ++d) {  // tile 1 DMA issued LAST (youngest 4 vm ops)
      const int k1 = tkrow[32 + d * 8 + keyBase];
      ldsdma16(kvb + (size_t)k1 * 576 + cA, &St[1][d * 4096 + tid * 8]);
    }
  }
  int sti = 0, stp = 2;  // read buffer, prefetch buffer (=(ks+2)%3)
  for (int ks = 0; ks < 16; ++ks) {
    // DMA(ks) is >=12 vm ops old; vmcnt(4) leaves only the newest tile's DMA
    // (issued last previous iter) in flight.
    asm volatile("s_waitcnt vmcnt(4)" ::: "memory");
    __builtin_amdgcn_s_barrier();  // St[sti] full for all waves; St[stp] free
    const unsigned int tra = tra0 + sti * 32768;
    uint32x2 rl0, rl1, rl2, rl3, rl4, rl5, rl6, rl7;
    uint32x2 rh0, rh1, rh2, rh3, rh4, rh5, rh6, rh7;
    TR64(rl0, tra, "0");    TR64(rh0, tra, "4096");
    TR64(rl1, tra, "128");  TR64(rh1, tra, "4224");
    TR64(rl2, tra, "256");  TR64(rh2, tra, "4352");
    TR64(rl3, tra, "384");  TR64(rh3, tra, "4480");
    TR64(rl4, tra, "512");  TR64(rh4, tra, "4608");
    TR64(rl5, tra, "640");  TR64(rh5, tra, "4736");
    TR64(rl6, tra, "768");  TR64(rh6, tra, "4864");
    TR64(rl7, tra, "896");  TR64(rh7, tra, "4992");
    if (ks < 15) {
#pragma unroll
      for (int i = 0; i < 4; ++i)
        a_nxt[i] = *reinterpret_cast<const bf16x8*>(
            a_base + ((size_t)(ks + 1) * 128 + i * 16) * 32);
    }
    if (ks < 14) {
      const int d0 = ip0, d1 = ip1, d2 = ip2, d3 = ip3;
      if (ks < 13) {
        ip0 = tkrow[(ks + 3) * 32 + 0 * 8 + keyBase];
        ip1 = tkrow[(ks + 3) * 32 + 1 * 8 + keyBase];
        ip2 = tkrow[(ks + 3) * 32 + 2 * 8 + keyBase];
        ip3 = tkrow[(ks + 3) * 32 + 3 * 8 + keyBase];
      }
      // DMA issued last so it stays the youngest vm group
      ldsdma16(kvb + (size_t)d0 * 576 + cA, &St[stp][0 * 4096 + tid * 8]);
      ldsdma16(kvb + (size_t)d1 * 576 + cA, &St[stp][1 * 4096 + tid * 8]);
      ldsdma16(kvb + (size_t)d2 * 576 + cA, &St[stp][2 * 4096 + tid * 8]);
      ldsdma16(kvb + (size_t)d3 * 576 + cA, &St[stp][3 * 4096 + tid * 8]);
    }
    asm volatile("s_waitcnt lgkmcnt(0)");   // tr_reads complete
    __builtin_amdgcn_sched_barrier(0);      // rule #18: pin MFMAs after the wait
    bf16x8 bfr[8];
    {
      uint32x4 w;
      w.x = rl0.x; w.y = rl0.y; w.z = rh0.x; w.w = rh0.y; bfr[0] = __builtin_bit_cast(bf16x8, w);
      w.x = rl1.x; w.y = rl1.y; w.z = rh1.x; w.w = rh1.y; bfr[1] = __builtin_bit_cast(bf16x8, w);
      w.x = rl2.x; w.y = rl2.y; w.z = rh2.x; w.w = rh2.y; bfr[2] = __builtin_bit_cast(bf16x8, w);
      w.x = rl3.x; w.y = rl3.y; w.z = rh3.x; w.w = rh3.y; bfr[3] = __builtin_bit_cast(bf16x8, w);
      w.x = rl4.x; w.y = rl4.y; w.z = rh4.x; w.w = rh4.y; bfr[4] = __builtin_bit_cast(bf16x8, w);
      w.x = rl5.x; w.y = rl5.y; w.z = rh5.x; w.w = rh5.y; bfr[5] = __builtin_bit_cast(bf16x8, w);
      w.x = rl6.x; w.y = rl6.y; w.z = rh6.x; w.w = rh6.y; bfr[6] = __builtin_bit_cast(bf16x8, w);
      w.x = rl7.x; w.y = rl7.y; w.z = rh7.x; w.w = rh7.y; bfr[7] = __builtin_bit_cast(bf16x8, w);
    }
#pragma unroll
    for (int i = 0; i < 4; ++i)
#pragma unroll
      for (int j = 0; j < 8; ++j)
        acc[i][j] =
            __builtin_amdgcn_mfma_f32_16x16x32_bf16(a_cur[i], bfr[j], acc[i][j], 0, 0, 0);
#pragma unroll
    for (int i = 0; i < 4; ++i) a_cur[i] = a_nxt[i];
    sti = sti == 2 ? 0 : sti + 1;
    stp = stp == 2 ? 0 : stp + 1;
  }
  // write attn_lat in (H, T, 512) layout for K5's contiguous A reads
#pragma unroll
  for (int i = 0; i < 4; ++i) {
    const int row = wm + i * 16 + quad * 4;  // head
#pragma unroll
    for (int j = 0; j < 8; ++j) {
      const int col = wc * 128 + j * 16 + l15;  // c
#pragma unroll
      for (int r = 0; r < 4; ++r)
        alat[((size_t)(row + r) * 512 + t) * 512 + col] = f2bf(acc[i][j][r]);
    }
  }
}

// ---------------- K5: out (128t x 128v tile) = attn_lat[h] @ v_b[h]^T ----------------
// grid (4, 128): y = h; the 4 token-tile blocks sharing B(h) are CONSECUTIVE.
__global__ __launch_bounds__(256) void out_gemm(const unsigned short* __restrict__ alat,
                                                const float* __restrict__ vb,
                                                float* __restrict__ out) {
  const int h = blockIdx.y;
  const int tm = blockIdx.x * 128;  // token tile
  __shared__ __align__(16) unsigned short As[128 * 32];
  __shared__ __align__(16) unsigned short Bs[128 * 32];
  const int tid = threadIdx.x;
  const int lane = tid & 63, wave = tid >> 6;
  const int wm = (wave & 1) * 64, wn = (wave >> 1) * 64;
  const int l15 = lane & 15, quad = lane >> 4;
  const int r0 = tid >> 2, cg = tid & 3;
  const unsigned short* a0 = alat + ((size_t)h * 512 + tm + r0) * 512 + cg * 8;
  const unsigned short* a1 = a0 + (size_t)64 * 512;
  const float* b0 = vb + ((size_t)h * 128 + r0) * 512 + cg * 8;
  const float* b1 = b0 + (size_t)64 * 512;
  floatx4 acc[4][4] = {};
  for (int ks = 0; ks < 16; ++ks) {  // contraction 512 = 16*32
    ldsdma16(a0 + ks * 32, &As[tid * 8]);
    ldsdma16(a1 + ks * 32, &As[2048 + tid * 8]);
    stage8_f32(b0 + ks * 32, &Bs[tid * 8]);
    stage8_f32(b1 + ks * 32, &Bs[2048 + tid * 8]);
    __syncthreads();
    mfma_4x4(As, Bs, wm, wn, l15, quad, acc);
    __syncthreads();
  }
#pragma unroll
  for (int i = 0; i < 4; ++i) {
    const int row = wm + i * 16 + quad * 4;  // token-local
#pragma unroll
    for (int j = 0; j < 4; ++j) {
      const int col = wn + j * 16 + l15;  // v
#pragma unroll
      for (int r = 0; r < 4; ++r) {
        const int t = tm + row + r;
        out[((size_t)t * 128 + h) * 128 + col] = acc[i][j][r];
      }
    }
  }
}

extern "C" void kernel_launch(void* const* d_in, const int* in_sizes, int n_in,
                              void* d_out, int out_size, void* d_ws, size_t ws_size,
                              hipStream_t stream) {
  const float* q = (const float*)d_in[0];         // (512,128,192)
  const float* kv = (const float*)d_in[1];        // (8192,576)
  const int* topk = (const int*)d_in[2];          // (512,512)
  const float* kb = (const float*)d_in[3];        // (128,512,128)
  const float* vb = (const float*)d_in[4];        // (128,128,512)
  float* out = (float*)d_out;                     // (512,128,128)

  char* ws = (char*)d_ws;
  unsigned short* kvb = (unsigned short*)ws;                       // 9,437,184 B
  unsigned short* qc = (unsigned short*)(ws + 9437184);            // 75,497,472 B
  unsigned short* P = (unsigned short*)(ws + 9437184 + 75497472);  // 67,108,864 B
  // lifetime reuse (no growth, 152 MB total):
  unsigned short* P2 = qc;    // qc dead after scores_gemm; softmax writes here
  unsigned short* alat = P;   // P dead after softmax; attn writes here

  prep<<<dim3(20992), dim3(256), 0, stream>>>(kv, kvb, q, qc);
  qlat_gemm<<<dim3(16, 128), dim3(256), 0, stream>>>(q, kb, qc);
  scores_gemm<<<dim3(4, 512), dim3(256), 0, stream>>>(qc, kvb, topk, P);
  softmax_rows<<<dim3(16384), dim3(256), 0, stream>>>(P, P2);
  attn_gemm<<<dim3(512), dim3(512), 0, stream>>>(P2, kvb, topk, alat);
  out_gemm<<<dim3(4, 128), dim3(256), 0, stream>>>(alat, vb, out);
}